// Round 7
// baseline (229.237 us; speedup 1.0000x reference)
//
#include <hip/hip_runtime.h>
#include <math.h>

#define DD 256
#define MM 2048
#define NN 512

typedef float f32x4 __attribute__((ext_vector_type(4)));

__device__ inline f32x4 ld_nt(const f32x4* p) { return __builtin_nontemporal_load(p); }

// blocks 0..255:   W1[d][j]  = (1/16) * sum_a wq[a][d]*wk[a][j]   (qt = q_vec @ W1)
// blocks 256..511: W2T[d][j] = sum_e wo[j][e]*wv[e][d]            (out = c @ W2T)
__global__ void prep_weights(const float* __restrict__ wq, const float* __restrict__ wk,
                             const float* __restrict__ wv, const float* __restrict__ wo,
                             float* __restrict__ W1, float* __restrict__ W2T) {
    __shared__ float sA[DD];
    const int j = threadIdx.x;
    const int b = blockIdx.x;
    if (b < DD) {
        const int d = b;
        sA[j] = wq[j * DD + d];
        __syncthreads();
        float acc = 0.f;
        for (int a = 0; a < DD; ++a) acc = fmaf(sA[a], wk[a * DD + j], acc);
        W1[d * DD + j] = acc * 0.0625f;
    } else {
        const int d = b - DD;
        sA[j] = wv[j * DD + d];
        __syncthreads();
        float acc = 0.f;
        for (int e = 0; e < DD; ++e) acc = fmaf(wo[j * DD + e], sA[e], acc);
        W2T[d * DD + j] = acc;
    }
}

// EXACT R3 (208.8us) kernel. The ONLY experiment this round is launch-side:
// +48KB dynamic LDS pads the block footprint to 56.2KB -> 2 blocks/CU,
// halving concurrent DRAM read streams (1024 -> 512) to test whether
// stream-count / row-buffer locality is what caps us at ~5.4 TB/s.
__global__ __launch_bounds__(256, 4)
void attn_fused(const float* __restrict__ q_vec, const float* __restrict__ kv,
                const float* __restrict__ W1, const float* __restrict__ W2T,
                float* __restrict__ out, float* __restrict__ attn_out) {
    __shared__ float s_pe[NN];
    __shared__ float s_lw[4];
    __shared__ float s_wc[4][DD];
    __shared__ float s_q[DD];
    __shared__ float s_qt[DD];

    const int m    = blockIdx.x;
    const int tid  = threadIdx.x;
    const int wave = tid >> 6;
    const int lane = tid & 63;
    const int grp  = lane >> 4;
    const int l16  = lane & 15;
    const int nbase = wave * 4 + grp;

    // ---- prologue: qt[m] = q_vec[m] @ W1 ----
    s_q[tid] = q_vec[(size_t)m * DD + tid];
    __syncthreads();
    {
        float a = 0.f;
#pragma unroll 8
        for (int d = 0; d < DD; ++d) a = fmaf(s_q[d], W1[d * DD + tid], a);
        s_qt[tid] = a;
    }
    __syncthreads();

    const f32x4* qt4 = (const f32x4*)s_qt;
    const f32x4 qv0 = qt4[l16];
    const f32x4 qv1 = qt4[l16 + 16];
    const f32x4 qv2 = qt4[l16 + 32];
    const f32x4 qv3 = qt4[l16 + 48];

    const f32x4* p = (const f32x4*)(kv + (size_t)m * NN * DD) + (size_t)nbase * 64 + l16;
    const int STRIDE = 16 * 64;   // 16 rows per iteration, in float4 units

    f32x4 c0 = (f32x4)0.f, c1 = (f32x4)0.f, c2 = (f32x4)0.f, c3 = (f32x4)0.f;
    float lw = 0.f;

    f32x4 a0 = ld_nt(p), a1 = ld_nt(p + 16), a2 = ld_nt(p + 32), a3 = ld_nt(p + 48);

#pragma unroll 2
    for (int it = 0; it < NN / 16; ++it) {
        f32x4 b0, b1, b2, b3;
        if (it + 1 < NN / 16) {
            const f32x4* np = p + (size_t)(it + 1) * STRIDE;
            b0 = ld_nt(np); b1 = ld_nt(np + 16); b2 = ld_nt(np + 32); b3 = ld_nt(np + 48);
        }
        f32x4 t = a0 * qv0 + a1 * qv1 + a2 * qv2 + a3 * qv3;
        float pd = (t[0] + t[1]) + (t[2] + t[3]);
        pd += __shfl_xor(pd, 1);
        pd += __shfl_xor(pd, 2);
        pd += __shfl_xor(pd, 4);
        pd += __shfl_xor(pd, 8);

        const float pe = __expf(pd);
        if (l16 == 0) s_pe[it * 16 + nbase] = pe;
        lw += pe;

        c0 += pe * a0;
        c1 += pe * a1;
        c2 += pe * a2;
        c3 += pe * a3;

        a0 = b0; a1 = b1; a2 = b2; a3 = b3;
    }

    // cross-group reduce within the wave (lanes ^16, ^32)
#pragma unroll
    for (int i = 0; i < 4; ++i) {
        c0[i] += __shfl_xor(c0[i], 16); c1[i] += __shfl_xor(c1[i], 16);
        c2[i] += __shfl_xor(c2[i], 16); c3[i] += __shfl_xor(c3[i], 16);
        c0[i] += __shfl_xor(c0[i], 32); c1[i] += __shfl_xor(c1[i], 32);
        c2[i] += __shfl_xor(c2[i], 32); c3[i] += __shfl_xor(c3[i], 32);
    }
    lw += __shfl_xor(lw, 16);
    lw += __shfl_xor(lw, 32);

    {
        f32x4* wc4 = (f32x4*)(&s_wc[wave][0]);
        const f32x4 cg = (grp == 0) ? c0 : (grp == 1) ? c1 : (grp == 2) ? c2 : c3;
        wc4[grp * 16 + l16] = cg;
        if (lane == 0) s_lw[wave] = lw;
    }
    __syncthreads();

    const float L = (s_lw[0] + s_lw[1]) + (s_lw[2] + s_lw[3]);
    const float invL = 1.f / L;

    const float cd = ((s_wc[0][tid] + s_wc[1][tid]) + (s_wc[2][tid] + s_wc[3][tid])) * invL;
    __syncthreads();
    s_q[tid] = cd;                       // reuse s_q as normalized c row
    __syncthreads();

    attn_out[(size_t)m * NN + tid]       = s_pe[tid] * invL;
    attn_out[(size_t)m * NN + tid + 256] = s_pe[tid + 256] * invL;

    // ---- epilogue: out[m] = c @ W2T ----
    float o = 0.f;
#pragma unroll 8
    for (int d = 0; d < DD; ++d) o = fmaf(s_q[d], W2T[d * DD + tid], o);
    out[(size_t)m * DD + tid] = o;
}

extern "C" void kernel_launch(void* const* d_in, const int* in_sizes, int n_in,
                              void* d_out, int out_size, void* d_ws, size_t ws_size,
                              hipStream_t stream) {
    const float* q_vec = (const float*)d_in[0];
    const float* kv    = (const float*)d_in[1];
    const float* wq    = (const float*)d_in[2];
    const float* wk    = (const float*)d_in[3];
    const float* wv    = (const float*)d_in[4];
    const float* wo    = (const float*)d_in[5];

    float* out  = (float*)d_out;                     // [M, D]
    float* attn = (float*)d_out + (size_t)MM * DD;   // [M, N]

    float* W1  = (float*)d_ws;                       // [D, D] (1/16 folded)
    float* W2T = W1 + DD * DD;                       // [D, D] = (wo@wv).T

    prep_weights<<<2 * DD, DD, 0, stream>>>(wq, wk, wv, wo, W1, W2T);
    // 48KB dynamic LDS pad: static 8.2KB + 48KB = 56.2KB -> 2 blocks/CU.
    attn_fused<<<MM, DD, 48 * 1024, stream>>>(q_vec, kv, W1, W2T, out, attn);
}

// Round 8
// 224.638 us; speedup vs baseline: 1.0205x; 1.0205x over previous
//
#include <hip/hip_runtime.h>
#include <math.h>

#define DD 256
#define MM 2048
#define NN 512

typedef float f32x4 __attribute__((ext_vector_type(4)));

__device__ inline f32x4 ld_nt(const f32x4* p) { return __builtin_nontemporal_load(p); }

// blocks 0..255:   W1[d][j]  = (1/16) * sum_a wq[a][d]*wk[a][j]   (qt = q_vec @ W1)
// blocks 256..511: W2T[d][j] = sum_e wo[j][e]*wv[e][d]            (out = c @ W2T)
__global__ void prep_weights(const float* __restrict__ wq, const float* __restrict__ wk,
                             const float* __restrict__ wv, const float* __restrict__ wo,
                             float* __restrict__ W1, float* __restrict__ W2T) {
    __shared__ float sA[DD];
    const int j = threadIdx.x;
    const int b = blockIdx.x;
    if (b < DD) {
        const int d = b;
        sA[j] = wq[j * DD + d];
        __syncthreads();
        float acc = 0.f;
        for (int a = 0; a < DD; ++a) acc = fmaf(sA[a], wk[a * DD + j], acc);
        W1[d * DD + j] = acc * 0.0625f;
    } else {
        const int d = b - DD;
        sA[j] = wv[j * DD + d];
        __syncthreads();
        float acc = 0.f;
        for (int e = 0; e < DD; ++e) acc = fmaf(wo[j * DD + e], sA[e], acc);
        W2T[d * DD + j] = acc;
    }
}

// EXACT R3 (208.8us) kernel, templated ONLY on the kv load policy.
// A/B this round: first half-grid uses nontemporal loads (R3 config),
// second half uses plain loads. Any total-time drop vs 208.8 => plain wins.
template <bool USE_NT>
__global__ __launch_bounds__(256, 4)
void attn_fused(const float* __restrict__ q_vec, const float* __restrict__ kv,
                const float* __restrict__ W1, const float* __restrict__ W2T,
                float* __restrict__ out, float* __restrict__ attn_out, int m_base) {
    __shared__ float s_pe[NN];
    __shared__ float s_lw[4];
    __shared__ float s_wc[4][DD];
    __shared__ float s_q[DD];
    __shared__ float s_qt[DD];

    const int m    = m_base + blockIdx.x;
    const int tid  = threadIdx.x;
    const int wave = tid >> 6;
    const int lane = tid & 63;
    const int grp  = lane >> 4;
    const int l16  = lane & 15;
    const int nbase = wave * 4 + grp;

    // ---- prologue: qt[m] = q_vec[m] @ W1 ----
    s_q[tid] = q_vec[(size_t)m * DD + tid];
    __syncthreads();
    {
        float a = 0.f;
#pragma unroll 8
        for (int d = 0; d < DD; ++d) a = fmaf(s_q[d], W1[d * DD + tid], a);
        s_qt[tid] = a;
    }
    __syncthreads();

    const f32x4* qt4 = (const f32x4*)s_qt;
    const f32x4 qv0 = qt4[l16];
    const f32x4 qv1 = qt4[l16 + 16];
    const f32x4 qv2 = qt4[l16 + 32];
    const f32x4 qv3 = qt4[l16 + 48];

    const f32x4* p = (const f32x4*)(kv + (size_t)m * NN * DD) + (size_t)nbase * 64 + l16;
    const int STRIDE = 16 * 64;   // 16 rows per iteration, in float4 units

    f32x4 c0 = (f32x4)0.f, c1 = (f32x4)0.f, c2 = (f32x4)0.f, c3 = (f32x4)0.f;
    float lw = 0.f;

#define LD(q) (USE_NT ? ld_nt(q) : *(q))
    f32x4 a0 = LD(p), a1 = LD(p + 16), a2 = LD(p + 32), a3 = LD(p + 48);

#pragma unroll 2
    for (int it = 0; it < NN / 16; ++it) {
        f32x4 b0, b1, b2, b3;
        if (it + 1 < NN / 16) {
            const f32x4* np = p + (size_t)(it + 1) * STRIDE;
            b0 = LD(np); b1 = LD(np + 16); b2 = LD(np + 32); b3 = LD(np + 48);
        }
        f32x4 t = a0 * qv0 + a1 * qv1 + a2 * qv2 + a3 * qv3;
        float pd = (t[0] + t[1]) + (t[2] + t[3]);
        pd += __shfl_xor(pd, 1);
        pd += __shfl_xor(pd, 2);
        pd += __shfl_xor(pd, 4);
        pd += __shfl_xor(pd, 8);

        const float pe = __expf(pd);
        if (l16 == 0) s_pe[it * 16 + nbase] = pe;
        lw += pe;

        c0 += pe * a0;
        c1 += pe * a1;
        c2 += pe * a2;
        c3 += pe * a3;

        a0 = b0; a1 = b1; a2 = b2; a3 = b3;
    }
#undef LD

    // cross-group reduce within the wave (lanes ^16, ^32)
#pragma unroll
    for (int i = 0; i < 4; ++i) {
        c0[i] += __shfl_xor(c0[i], 16); c1[i] += __shfl_xor(c1[i], 16);
        c2[i] += __shfl_xor(c2[i], 16); c3[i] += __shfl_xor(c3[i], 16);
        c0[i] += __shfl_xor(c0[i], 32); c1[i] += __shfl_xor(c1[i], 32);
        c2[i] += __shfl_xor(c2[i], 32); c3[i] += __shfl_xor(c3[i], 32);
    }
    lw += __shfl_xor(lw, 16);
    lw += __shfl_xor(lw, 32);

    {
        f32x4* wc4 = (f32x4*)(&s_wc[wave][0]);
        const f32x4 cg = (grp == 0) ? c0 : (grp == 1) ? c1 : (grp == 2) ? c2 : c3;
        wc4[grp * 16 + l16] = cg;
        if (lane == 0) s_lw[wave] = lw;
    }
    __syncthreads();

    const float L = (s_lw[0] + s_lw[1]) + (s_lw[2] + s_lw[3]);
    const float invL = 1.f / L;

    const float cd = ((s_wc[0][tid] + s_wc[1][tid]) + (s_wc[2][tid] + s_wc[3][tid])) * invL;
    __syncthreads();
    s_q[tid] = cd;                       // reuse s_q as normalized c row
    __syncthreads();

    attn_out[(size_t)m * NN + tid]       = s_pe[tid] * invL;
    attn_out[(size_t)m * NN + tid + 256] = s_pe[tid + 256] * invL;

    // ---- epilogue: out[m] = c @ W2T ----
    float o = 0.f;
#pragma unroll 8
    for (int d = 0; d < DD; ++d) o = fmaf(s_q[d], W2T[d * DD + tid], o);
    out[(size_t)m * DD + tid] = o;
}

extern "C" void kernel_launch(void* const* d_in, const int* in_sizes, int n_in,
                              void* d_out, int out_size, void* d_ws, size_t ws_size,
                              hipStream_t stream) {
    const float* q_vec = (const float*)d_in[0];
    const float* kv    = (const float*)d_in[1];
    const float* wq    = (const float*)d_in[2];
    const float* wk    = (const float*)d_in[3];
    const float* wv    = (const float*)d_in[4];
    const float* wo    = (const float*)d_in[5];

    float* out  = (float*)d_out;                     // [M, D]
    float* attn = (float*)d_out + (size_t)MM * DD;   // [M, N]

    float* W1  = (float*)d_ws;                       // [D, D] (1/16 folded)
    float* W2T = W1 + DD * DD;                       // [D, D] = (wo@wv).T

    prep_weights<<<2 * DD, DD, 0, stream>>>(wq, wk, wv, wo, W1, W2T);
    // A/B: half the m-rows with nontemporal kv loads (R3 config), half plain.
    attn_fused<true ><<<MM / 2, DD, 0, stream>>>(q_vec, kv, W1, W2T, out, attn, 0);
    attn_fused<false><<<MM / 2, DD, 0, stream>>>(q_vec, kv, W1, W2T, out, attn, MM / 2);
}

// Round 9
// 208.307 us; speedup vs baseline: 1.1005x; 1.0784x over previous
//
#include <hip/hip_runtime.h>
#include <math.h>

#define DD 256
#define MM 2048
#define NN 512

typedef float f32x4 __attribute__((ext_vector_type(4)));

__device__ inline f32x4 ld_nt(const f32x4* p) { return __builtin_nontemporal_load(p); }

// blocks 0..255:   W1[d][j]  = (1/16) * sum_a wq[a][d]*wk[a][j]   (qt = q_vec @ W1)
// blocks 256..511: W2T[d][j] = sum_e wo[j][e]*wv[e][d]            (out = c @ W2T)
__global__ void prep_weights(const float* __restrict__ wq, const float* __restrict__ wk,
                             const float* __restrict__ wv, const float* __restrict__ wo,
                             float* __restrict__ W1, float* __restrict__ W2T) {
    __shared__ float sA[DD];
    const int j = threadIdx.x;
    const int b = blockIdx.x;
    if (b < DD) {
        const int d = b;
        sA[j] = wq[j * DD + d];
        __syncthreads();
        float acc = 0.f;
        for (int a = 0; a < DD; ++a) acc = fmaf(sA[a], wk[a * DD + j], acc);
        W1[d * DD + j] = acc * 0.0625f;
    } else {
        const int d = b - DD;
        sA[j] = wv[j * DD + d];
        __syncthreads();
        float acc = 0.f;
        for (int e = 0; e < DD; ++e) acc = fmaf(wo[j * DD + e], sA[e], acc);
        W2T[d * DD + j] = acc;
    }
}

// EXACT R3 (208.8us) kernel with ONE change: the tile-0 kv prefetch (4 nt
// loads) is hoisted ABOVE the qt-prologue, so HBM is busy during the block's
// ~3us L2-latency-bound W1 GEMV (kills the global t=0 head bubble).
__global__ __launch_bounds__(256, 4)
void attn_fused(const float* __restrict__ q_vec, const float* __restrict__ kv,
                const float* __restrict__ W1, const float* __restrict__ W2T,
                float* __restrict__ out, float* __restrict__ attn_out) {
    __shared__ float s_pe[NN];
    __shared__ float s_lw[4];
    __shared__ float s_wc[4][DD];
    __shared__ float s_q[DD];
    __shared__ float s_qt[DD];

    const int m    = blockIdx.x;
    const int tid  = threadIdx.x;
    const int wave = tid >> 6;
    const int lane = tid & 63;
    const int grp  = lane >> 4;
    const int l16  = lane & 15;
    const int nbase = wave * 4 + grp;

    const f32x4* p = (const f32x4*)(kv + (size_t)m * NN * DD) + (size_t)nbase * 64 + l16;
    const int STRIDE = 16 * 64;   // 16 rows per iteration, in float4 units

    // ---- tile-0 prefetch BEFORE the prologue ----
    f32x4 a0 = ld_nt(p), a1 = ld_nt(p + 16), a2 = ld_nt(p + 32), a3 = ld_nt(p + 48);

    // ---- prologue: qt[m] = q_vec[m] @ W1 ----
    s_q[tid] = q_vec[(size_t)m * DD + tid];
    __syncthreads();
    {
        float a = 0.f;
#pragma unroll 8
        for (int d = 0; d < DD; ++d) a = fmaf(s_q[d], W1[d * DD + tid], a);
        s_qt[tid] = a;
    }
    __syncthreads();

    const f32x4* qt4 = (const f32x4*)s_qt;
    const f32x4 qv0 = qt4[l16];
    const f32x4 qv1 = qt4[l16 + 16];
    const f32x4 qv2 = qt4[l16 + 32];
    const f32x4 qv3 = qt4[l16 + 48];

    f32x4 c0 = (f32x4)0.f, c1 = (f32x4)0.f, c2 = (f32x4)0.f, c3 = (f32x4)0.f;
    float lw = 0.f;

#pragma unroll 2
    for (int it = 0; it < NN / 16; ++it) {
        f32x4 b0, b1, b2, b3;
        if (it + 1 < NN / 16) {
            const f32x4* np = p + (size_t)(it + 1) * STRIDE;
            b0 = ld_nt(np); b1 = ld_nt(np + 16); b2 = ld_nt(np + 32); b3 = ld_nt(np + 48);
        }
        f32x4 t = a0 * qv0 + a1 * qv1 + a2 * qv2 + a3 * qv3;
        float pd = (t[0] + t[1]) + (t[2] + t[3]);
        pd += __shfl_xor(pd, 1);
        pd += __shfl_xor(pd, 2);
        pd += __shfl_xor(pd, 4);
        pd += __shfl_xor(pd, 8);

        const float pe = __expf(pd);
        if (l16 == 0) s_pe[it * 16 + nbase] = pe;
        lw += pe;

        c0 += pe * a0;
        c1 += pe * a1;
        c2 += pe * a2;
        c3 += pe * a3;

        a0 = b0; a1 = b1; a2 = b2; a3 = b3;
    }

    // cross-group reduce within the wave (lanes ^16, ^32)
#pragma unroll
    for (int i = 0; i < 4; ++i) {
        c0[i] += __shfl_xor(c0[i], 16); c1[i] += __shfl_xor(c1[i], 16);
        c2[i] += __shfl_xor(c2[i], 16); c3[i] += __shfl_xor(c3[i], 16);
        c0[i] += __shfl_xor(c0[i], 32); c1[i] += __shfl_xor(c1[i], 32);
        c2[i] += __shfl_xor(c2[i], 32); c3[i] += __shfl_xor(c3[i], 32);
    }
    lw += __shfl_xor(lw, 16);
    lw += __shfl_xor(lw, 32);

    {
        f32x4* wc4 = (f32x4*)(&s_wc[wave][0]);
        const f32x4 cg = (grp == 0) ? c0 : (grp == 1) ? c1 : (grp == 2) ? c2 : c3;
        wc4[grp * 16 + l16] = cg;
        if (lane == 0) s_lw[wave] = lw;
    }
    __syncthreads();

    const float L = (s_lw[0] + s_lw[1]) + (s_lw[2] + s_lw[3]);
    const float invL = 1.f / L;

    const float cd = ((s_wc[0][tid] + s_wc[1][tid]) + (s_wc[2][tid] + s_wc[3][tid])) * invL;
    __syncthreads();
    s_q[tid] = cd;                       // reuse s_q as normalized c row
    __syncthreads();

    attn_out[(size_t)m * NN + tid]       = s_pe[tid] * invL;
    attn_out[(size_t)m * NN + tid + 256] = s_pe[tid + 256] * invL;

    // ---- epilogue: out[m] = c @ W2T ----
    float o = 0.f;
#pragma unroll 8
    for (int d = 0; d < DD; ++d) o = fmaf(s_q[d], W2T[d * DD + tid], o);
    out[(size_t)m * DD + tid] = o;
}

extern "C" void kernel_launch(void* const* d_in, const int* in_sizes, int n_in,
                              void* d_out, int out_size, void* d_ws, size_t ws_size,
                              hipStream_t stream) {
    const float* q_vec = (const float*)d_in[0];
    const float* kv    = (const float*)d_in[1];
    const float* wq    = (const float*)d_in[2];
    const float* wk    = (const float*)d_in[3];
    const float* wv    = (const float*)d_in[4];
    const float* wo    = (const float*)d_in[5];

    float* out  = (float*)d_out;                     // [M, D]
    float* attn = (float*)d_out + (size_t)MM * DD;   // [M, N]

    float* W1  = (float*)d_ws;                       // [D, D] (1/16 folded)
    float* W2T = W1 + DD * DD;                       // [D, D] = (wo@wv).T

    prep_weights<<<2 * DD, DD, 0, stream>>>(wq, wk, wv, wo, W1, W2T);
    attn_fused<<<MM, DD, 0, stream>>>(q_vec, kv, W1, W2T, out, attn);
}